// Round 3
// baseline (144.700 us; speedup 1.0000x reference)
//
#include <hip/hip_runtime.h>
#include <math.h>

// Problem constants (baked from reference setup_inputs):
// B=2, N=1024, Din=64, D=64, K=24
#define BB 2
#define NN 1024
#define DD 64
#define KK 24
#define NPTS (BB * NN)  // 2048

#if __has_builtin(__builtin_amdgcn_exp2f)
#define EXP2(x) __builtin_amdgcn_exp2f(x)
#else
#define EXP2(x) exp2f(x)
#endif

typedef float v2f __attribute__((ext_vector_type(2)));

// Force VOP3P packed f32 math (LLVM does not form these from ext_vector ops).
static __device__ __forceinline__ v2f pk_fma(v2f a, v2f b, v2f c) {
    v2f d;
    asm("v_pk_fma_f32 %0, %1, %2, %3" : "=v"(d) : "v"(a), "v"(b), "v"(c));
    return d;
}
static __device__ __forceinline__ v2f pk_add(v2f a, v2f b) {
    v2f d;
    asm("v_pk_add_f32 %0, %1, %2" : "=v"(d) : "v"(a), "v"(b));
    return d;
}

// ---------------------------------------------------------------------------
// Workspace layout (bytes):
//   feat : [2048][64] float   @ 0        (512 KiB)
//   idx  : [2048][24] int     @ 524288   (192 KiB)
//   rwP  : [4096] float4      @ 720896   (64 KiB)  {rw0,rw1,rw2,rb}*log2(e)
// ---------------------------------------------------------------------------

// Fused prep + MLP + KNN, role-split by blockIdx:
//   blocks [0,512)    : MLP, 4 points per block
//   blocks [512,528)  : rw/rb prescale+interleave
//   blocks [528,1040) : KNN, 4 points per block (one wave per point)
__global__ __launch_bounds__(256) void prep_mlp_knn_kernel(
    const float* __restrict__ feature, const float* __restrict__ xyz,
    const float* __restrict__ pw1, const float* __restrict__ pb1,
    const float* __restrict__ pw2, const float* __restrict__ pb2,
    const float* __restrict__ rw, const float* __restrict__ rb,
    float* __restrict__ feat, int* __restrict__ idx_out,
    float4* __restrict__ rwP) {
    int bid = blockIdx.x;
    int tid = threadIdx.x;

    if (bid < 512) {
        // ---- MLP: feat = relu(relu(feature@pw1+pb1)@pw2+pb2), 4 rows/block
        int r = tid >> 6;
        int d = tid & 63;
        int row = bid * 4 + r;
        __shared__ float s_in[4][64];
        __shared__ float s_h[4][64];
        s_in[r][d] = feature[row * 64 + d];
        __syncthreads();
        float h = pb1[d];
#pragma unroll
        for (int i = 0; i < 64; i++) h = __builtin_fmaf(s_in[r][i], pw1[i * 64 + d], h);
        h = fmaxf(h, 0.f);
        s_h[r][d] = h;
        __syncthreads();
        float f = pb2[d];
#pragma unroll
        for (int i = 0; i < 64; i++) f = __builtin_fmaf(s_h[r][i], pw2[i * 64 + d], f);
        f = fmaxf(f, 0.f);
        feat[row * 64 + d] = f;
    } else if (bid < 528) {
        // ---- prescale rw/rb by log2(e), interleave to float4 per column
        const float LOG2E = 1.4426950408889634f;
        int t = (bid - 512) * 256 + tid;  // 0..4095
        float4 v;
        v.x = rw[t] * LOG2E;
        v.y = rw[4096 + t] * LOG2E;
        v.z = rw[8192 + t] * LOG2E;
        v.w = rb[t] * LOG2E;
        rwP[t] = v;
    } else {
        // ---- KNN: one wave per point, iterative argmin (24 rounds)
        int w = tid >> 6;
        int lane = tid & 63;
        int pt = (bid - 528) * 4 + w;
        int b = pt >> 10;
        int n = pt & 1023;
        const float* xb = xyz + (size_t)b * NN * 3;
        float xn = xb[n * 3 + 0], yn = xb[n * 3 + 1], zn = xb[n * 3 + 2];
        float sqn = xn * xn + yn * yn + zn * zn;
        float dist[16];
#pragma unroll
        for (int c = 0; c < 16; c++) {
            int m = c * 64 + lane;
            float xm = xb[m * 3 + 0], ym = xb[m * 3 + 1], zm = xb[m * 3 + 2];
            float sqm = xm * xm + ym * ym + zm * zm;
            float dot = xn * xm + yn * ym + zn * zm;
            dist[c] = sqn + sqm - 2.0f * dot;
        }
        for (int r = 0; r < KK; r++) {
            float best = 3.4e38f;
            int bi = 1 << 30;
#pragma unroll
            for (int c = 0; c < 16; c++) {
                if (dist[c] < best) {  // strict < keeps lowest index on ties
                    best = dist[c];
                    bi = c * 64 + lane;
                }
            }
#pragma unroll
            for (int off = 32; off >= 1; off >>= 1) {
                float ob = __shfl_down(best, off);
                int oi = __shfl_down(bi, off);
                if (ob < best || (ob == best && oi < bi)) {
                    best = ob;
                    bi = oi;
                }
            }
            bi = __shfl(bi, 0);
            if ((bi & 63) == lane) dist[bi >> 6] = 3.4e38f;
            if (lane == 0) idx_out[pt * KK + r] = bi;
        }
    }
}

// Fused weight-gen + softmax (over K*D, per column d) + aggregate + final
// linear. One block (4 waves) per point; lane = d.
//
// R7 restructure (k-split): rounds 0-2 proved the j-split layout (wave owns
// 16 j's, all K) needs ~72 loop-invariant VGPRs for rel; the allocator
// refuses to allocate past 64 even with waves_per_eu(4,4) (VGPR_Count
// stayed 64, SGPR moved 32->112, dur unchanged) — it sinks the rel loads
// into the hot loop as per-use LDS re-reads, saturating the LDS pipe
// (VALUBusy stuck ~60%). Fix by decomposition, not allocator flags:
// wave w owns k in [6w, 6w+6) for ALL j=0..63. rel drops to 9 v2f = 18
// VGPRs; total live set ~55 regs fits the 64-reg/8-wave budget naturally.
// s_red cross-wave reduction is unchanged (partials partition (k,j) either
// way). g-values repacked [4][64][8] so each wave's 6 floats per j are one
// b128 + one b64 uniform (broadcast) read. rwP column per (wave,j): 64
// coalesced float4 loads, L2-hot, rolling 2-deep prefetch.
__global__ __launch_bounds__(256) void agg_kernel(const float* __restrict__ xyz,
                                                  const float* __restrict__ feat,
                                                  const int* __restrict__ idx,
                                                  const float4* __restrict__ rwP,
                                                  const float* __restrict__ sw,
                                                  const float* __restrict__ sb,
                                                  float* __restrict__ out) {
    int pt = blockIdx.x;
    int b = pt >> 10;
    int n = pt & 1023;
    int tid = threadIdx.x;
    int w = tid >> 6;
    int d = tid & 63;

    __shared__ __align__(8) float s_relT[3][28];      // [c][k], padded
    __shared__ __align__(16) float s_gvt[4][64][8];   // [kgrp][j][kslot], 8 KiB
    __shared__ float s_red[8][64];
    __shared__ float s_pre[64];

    const float* xb = xyz + (size_t)b * NN * 3;
    if (tid < KK * 3) {
        int k = tid % KK, c = tid / KK;
        int nb = idx[pt * KK + k];
        s_relT[c][k] = xb[nb * 3 + c] - xb[n * 3 + c];
    }
    for (int t = tid; t < KK * 64; t += 256) {
        int k = t >> 6, j = t & 63;
        int nb = idx[pt * KK + k];
        s_gvt[k / 6][j][k % 6] = feat[((size_t)b * NN + nb) * 64 + j];
    }
    __syncthreads();

    // This wave's 3 rel k-pairs (k0 = 6w is even -> 8B-aligned v2f loads).
    int k0 = 6 * w;
    v2f rx[3], ry[3], rz[3];
#pragma unroll
    for (int p = 0; p < 3; p++) {
        rx[p] = *(const v2f*)&s_relT[0][k0 + 2 * p];
        ry[p] = *(const v2f*)&s_relT[1][k0 + 2 * p];
        rz[p] = *(const v2f*)&s_relT[2][k0 + 2 * p];
    }

    v2f l0 = {0.f, 0.f}, l1 = {0.f, 0.f}, l2 = {0.f, 0.f};
    v2f a0 = {0.f, 0.f}, a1 = {0.f, 0.f}, a2 = {0.f, 0.f};

    const float* gw = &s_gvt[w][0][0];  // row stride 8 floats (32B)
    // Rolling 2-deep prefetch of this lane's rwP column (j*64+d).
    float4 rv0 = rwP[0 * 64 + d];
    float4 rv1 = rwP[1 * 64 + d];
    for (int j = 0; j < 64; j++) {
        float4 rvn = rv1;
        if (j < 62) rvn = rwP[(j + 2) * 64 + d];
        v2f R0 = {rv0.x, rv0.x}, R1 = {rv0.y, rv0.y}, R2 = {rv0.z, rv0.z}, RB = {rv0.w, rv0.w};
        float4 gA = *(const float4*)(gw + j * 8);      // slots 0..3
        v2f gC = *(const v2f*)(gw + j * 8 + 4);        // slots 4,5
        v2f g0 = {gA.x, gA.y};
        v2f g1 = {gA.z, gA.w};
        v2f t0 = pk_fma(rx[0], R0, pk_fma(ry[0], R1, pk_fma(rz[0], R2, RB)));
        v2f t1 = pk_fma(rx[1], R0, pk_fma(ry[1], R1, pk_fma(rz[1], R2, RB)));
        v2f t2 = pk_fma(rx[2], R0, pk_fma(ry[2], R1, pk_fma(rz[2], R2, RB)));
        v2f e0 = {EXP2(t0.x), EXP2(t0.y)};
        v2f e1 = {EXP2(t1.x), EXP2(t1.y)};
        v2f e2 = {EXP2(t2.x), EXP2(t2.y)};
        l0 = pk_add(l0, e0);
        l1 = pk_add(l1, e1);
        l2 = pk_add(l2, e2);
        a0 = pk_fma(g0, e0, a0);
        a1 = pk_fma(g1, e1, a1);
        a2 = pk_fma(gC, e2, a2);
        rv0 = rv1;
        rv1 = rvn;
    }
    s_red[w][d] = l0.x + l0.y + l1.x + l1.y + l2.x + l2.y;
    s_red[4 + w][d] = a0.x + a0.y + a1.x + a1.y + a2.x + a2.y;
    __syncthreads();
    if (tid < 64) {
        float L = s_red[0][d] + s_red[1][d] + s_red[2][d] + s_red[3][d];
        float A = s_red[4][d] + s_red[5][d] + s_red[6][d] + s_red[7][d];
        s_pre[d] = A / L;
    }
    __syncthreads();
    // out[pt][d] = sum_dd s_pre[dd] * sw[dd][d] + sb[d]
    float part = 0.f;
#pragma unroll
    for (int dd = 0; dd < 16; dd++) {
        int drow = w * 16 + dd;
        part = __builtin_fmaf(s_pre[drow], sw[drow * 64 + d], part);
    }
    s_red[w][d] = part;
    __syncthreads();
    if (tid < 64) {
        float o = s_red[0][d] + s_red[1][d] + s_red[2][d] + s_red[3][d] + sb[d];
        out[(size_t)pt * 64 + d] = o;
    }
    if (pt == 0 && tid == 0) out[(size_t)NPTS * 64] = 1024.0f;  // second output: N
}

extern "C" void kernel_launch(void* const* d_in, const int* in_sizes, int n_in,
                              void* d_out, int out_size, void* d_ws, size_t ws_size,
                              hipStream_t stream) {
    const float* feature = (const float*)d_in[0];
    const float* xyz = (const float*)d_in[1];
    const float* pw1 = (const float*)d_in[2];
    const float* pb1 = (const float*)d_in[3];
    const float* pw2 = (const float*)d_in[4];
    const float* pb2 = (const float*)d_in[5];
    const float* rw = (const float*)d_in[6];
    const float* rb = (const float*)d_in[7];
    const float* sw = (const float*)d_in[8];
    const float* sb = (const float*)d_in[9];
    float* out = (float*)d_out;

    char* ws = (char*)d_ws;
    float* feat = (float*)(ws);             // 512 KiB
    int* idx = (int*)(ws + 524288);         // 192 KiB
    float4* rwP = (float4*)(ws + 720896);   // 64 KiB

    prep_mlp_knn_kernel<<<1040, 256, 0, stream>>>(feature, xyz, pw1, pb1, pw2, pb2,
                                                  rw, rb, feat, idx, rwP);
    agg_kernel<<<NPTS, 256, 0, stream>>>(xyz, feat, idx, rwP, sw, sb, out);
}

// Round 4
// 133.326 us; speedup vs baseline: 1.0853x; 1.0853x over previous
//
#include <hip/hip_runtime.h>
#include <math.h>

// Problem constants (baked from reference setup_inputs):
// B=2, N=1024, Din=64, D=64, K=24
#define BB 2
#define NN 1024
#define DD 64
#define KK 24
#define NPTS (BB * NN)  // 2048

#if __has_builtin(__builtin_amdgcn_exp2f)
#define EXP2(x) __builtin_amdgcn_exp2f(x)
#else
#define EXP2(x) exp2f(x)
#endif

typedef float v2f __attribute__((ext_vector_type(2)));

// VOP3P packed f32 FMA with op_sel half-broadcasts of src1/src2.
// op_sel bit=1 -> lane-lo result uses HI half of that src; op_sel_hi bit=1 ->
// lane-hi uses HI half. Defaults [0,0,0]/[1,1,1] = normal packed.
static __device__ __forceinline__ v2f pk_fma(v2f a, v2f b, v2f c) {
    v2f d;
    asm("v_pk_fma_f32 %0, %1, %2, %3" : "=v"(d) : "v"(a), "v"(b), "v"(c));
    return d;
}
// d = a * bcast(lo(s)) + c
static __device__ __forceinline__ v2f pk_fma_s1lo(v2f a, v2f s, v2f c) {
    v2f d;
    asm("v_pk_fma_f32 %0, %1, %2, %3 op_sel_hi:[1,0,1]" : "=v"(d) : "v"(a), "v"(s), "v"(c));
    return d;
}
// d = a * bcast(hi(s)) + c
static __device__ __forceinline__ v2f pk_fma_s1hi(v2f a, v2f s, v2f c) {
    v2f d;
    asm("v_pk_fma_f32 %0, %1, %2, %3 op_sel:[0,1,0] op_sel_hi:[1,1,1]" : "=v"(d) : "v"(a), "v"(s), "v"(c));
    return d;
}
// d = a * bcast(lo(s)) + bcast(hi(s))   (weight-gen inner: rz*rw2 + rb)
static __device__ __forceinline__ v2f pk_fma_s1lo_s2hi(v2f a, v2f s) {
    v2f d;
    asm("v_pk_fma_f32 %0, %1, %2, %3 op_sel:[0,0,1] op_sel_hi:[1,0,1]" : "=v"(d) : "v"(a), "v"(s), "v"(s));
    return d;
}
static __device__ __forceinline__ v2f pk_add(v2f a, v2f b) {
    v2f d;
    asm("v_pk_add_f32 %0, %1, %2" : "=v"(d) : "v"(a), "v"(b));
    return d;
}

// 16B weight quad as two even-aligned v2f pairs: p01={rw0,rw1}, p23={rw2,rb}.
struct __align__(16) wq {
    v2f p01, p23;
};

// ---------------------------------------------------------------------------
// Workspace layout (bytes):
//   feat : [2048][64] float   @ 0        (512 KiB)
//   idx  : [2048][24] int     @ 524288   (192 KiB)
//   rwP  : [4096] float4      @ 720896   (64 KiB)  {rw0,rw1,rw2,rb}*log2(e)
// ---------------------------------------------------------------------------

// Fused prep + MLP + KNN, role-split by blockIdx:
//   blocks [0,512)    : MLP, 4 points per block
//   blocks [512,528)  : rw/rb prescale+interleave
//   blocks [528,1040) : KNN, 4 points per block (one wave per point)
__global__ __launch_bounds__(256) void prep_mlp_knn_kernel(
    const float* __restrict__ feature, const float* __restrict__ xyz,
    const float* __restrict__ pw1, const float* __restrict__ pb1,
    const float* __restrict__ pw2, const float* __restrict__ pb2,
    const float* __restrict__ rw, const float* __restrict__ rb,
    float* __restrict__ feat, int* __restrict__ idx_out,
    float4* __restrict__ rwP) {
    int bid = blockIdx.x;
    int tid = threadIdx.x;

    if (bid < 512) {
        // ---- MLP: feat = relu(relu(feature@pw1+pb1)@pw2+pb2), 4 rows/block
        int r = tid >> 6;
        int d = tid & 63;
        int row = bid * 4 + r;
        __shared__ float s_in[4][64];
        __shared__ float s_h[4][64];
        s_in[r][d] = feature[row * 64 + d];
        __syncthreads();
        float h = pb1[d];
#pragma unroll
        for (int i = 0; i < 64; i++) h = __builtin_fmaf(s_in[r][i], pw1[i * 64 + d], h);
        h = fmaxf(h, 0.f);
        s_h[r][d] = h;
        __syncthreads();
        float f = pb2[d];
#pragma unroll
        for (int i = 0; i < 64; i++) f = __builtin_fmaf(s_h[r][i], pw2[i * 64 + d], f);
        f = fmaxf(f, 0.f);
        feat[row * 64 + d] = f;
    } else if (bid < 528) {
        // ---- prescale rw/rb by log2(e), interleave to float4 per column
        const float LOG2E = 1.4426950408889634f;
        int t = (bid - 512) * 256 + tid;  // 0..4095
        float4 v;
        v.x = rw[t] * LOG2E;
        v.y = rw[4096 + t] * LOG2E;
        v.z = rw[8192 + t] * LOG2E;
        v.w = rb[t] * LOG2E;
        rwP[t] = v;
    } else {
        // ---- KNN: one wave per point, iterative argmin (24 rounds)
        int w = tid >> 6;
        int lane = tid & 63;
        int pt = (bid - 528) * 4 + w;
        int b = pt >> 10;
        int n = pt & 1023;
        const float* xb = xyz + (size_t)b * NN * 3;
        float xn = xb[n * 3 + 0], yn = xb[n * 3 + 1], zn = xb[n * 3 + 2];
        float sqn = xn * xn + yn * yn + zn * zn;
        float dist[16];
#pragma unroll
        for (int c = 0; c < 16; c++) {
            int m = c * 64 + lane;
            float xm = xb[m * 3 + 0], ym = xb[m * 3 + 1], zm = xb[m * 3 + 2];
            float sqm = xm * xm + ym * ym + zm * zm;
            float dot = xn * xm + yn * ym + zn * zm;
            dist[c] = sqn + sqm - 2.0f * dot;
        }
        for (int r = 0; r < KK; r++) {
            float best = 3.4e38f;
            int bi = 1 << 30;
#pragma unroll
            for (int c = 0; c < 16; c++) {
                if (dist[c] < best) {  // strict < keeps lowest index on ties
                    best = dist[c];
                    bi = c * 64 + lane;
                }
            }
#pragma unroll
            for (int off = 32; off >= 1; off >>= 1) {
                float ob = __shfl_down(best, off);
                int oi = __shfl_down(bi, off);
                if (ob < best || (ob == best && oi < bi)) {
                    best = ob;
                    bi = oi;
                }
            }
            bi = __shfl(bi, 0);
            if ((bi & 63) == lane) dist[bi >> 6] = 3.4e38f;
            if (lane == 0) idx_out[pt * KK + r] = bi;
        }
    }
}

// Fused weight-gen + softmax (over K*D, per column d) + aggregate + final
// linear. One block (4 waves) per point; lane = d; wave w owns k in
// [6w, 6w+6) for ALL j (k-split: rel = 9 v2f = 18 regs, fits the 64-reg
// budget — R0-R2 proved the j-split's 72-reg rel set gets demoted to LDS).
//
// R8 fixes over R7's k-split (54.5us, busy-cycles +21K vs j-split):
//  - op_sel half-broadcast pk_fma: weight pairs {rw0,rw1},{rw2,rb} are used
//    directly, no splat v_movs (removes ~512 movs/thread ~= 8K cy/SIMD).
//  - 4-deep rwP prefetch ring, static indices (4-unrolled j-loop): ~500cy
//    cover > L2 latency; R7's 2-deep (~130cy) stalled every iter.
//  - s_gvt [4][64][12]: 48B row stride keeps 16B alignment; write conflicts
//    back to 8-way (R7's stride-8 was 16-way, conflicts 299K->692K).
__global__ __launch_bounds__(256) void agg_kernel(const float* __restrict__ xyz,
                                                  const float* __restrict__ feat,
                                                  const int* __restrict__ idx,
                                                  const float4* __restrict__ rwP,
                                                  const float* __restrict__ sw,
                                                  const float* __restrict__ sb,
                                                  float* __restrict__ out) {
    int pt = blockIdx.x;
    int b = pt >> 10;
    int n = pt & 1023;
    int tid = threadIdx.x;
    int w = tid >> 6;
    int d = tid & 63;

    __shared__ __align__(8) float s_relT[3][28];      // [c][k], padded
    __shared__ __align__(16) float s_gvt[4][64][12];  // [kgrp][j][kslot0..5 + pad], 12 KiB
    __shared__ float s_red[8][64];
    __shared__ float s_pre[64];

    const float* xb = xyz + (size_t)b * NN * 3;
    if (tid < KK * 3) {
        int k = tid % KK, c = tid / KK;
        int nb = idx[pt * KK + k];
        s_relT[c][k] = xb[nb * 3 + c] - xb[n * 3 + c];
    }
    for (int t = tid; t < KK * 64; t += 256) {
        int k = t >> 6, j = t & 63;
        int nb = idx[pt * KK + k];
        s_gvt[k / 6][j][k % 6] = feat[((size_t)b * NN + nb) * 64 + j];
    }
    __syncthreads();

    // This wave's 3 rel k-pairs (k0 = 6w is even -> 8B-aligned v2f loads).
    int k0 = 6 * w;
    v2f rx[3], ry[3], rz[3];
#pragma unroll
    for (int p = 0; p < 3; p++) {
        rx[p] = *(const v2f*)&s_relT[0][k0 + 2 * p];
        ry[p] = *(const v2f*)&s_relT[1][k0 + 2 * p];
        rz[p] = *(const v2f*)&s_relT[2][k0 + 2 * p];
    }

    v2f l0 = {0.f, 0.f}, l1 = {0.f, 0.f}, l2 = {0.f, 0.f};
    v2f a0 = {0.f, 0.f}, a1 = {0.f, 0.f}, a2 = {0.f, 0.f};

    const float* gw = &s_gvt[w][0][0];  // row stride 12 floats (48B)
    const float4* rcol = rwP + d;       // column walk: rcol[j*64]

#define LDW(J) (*(const wq*)&rcol[(J) * 64])
#define STEP(RV, J)                                                           \
    {                                                                         \
        const float* gp = gw + (J) * 12;                                      \
        v2f g0 = *(const v2f*)gp;                                             \
        v2f g1 = *(const v2f*)(gp + 2);                                       \
        v2f g2 = *(const v2f*)(gp + 4);                                       \
        v2f t0 = pk_fma_s1lo(rx[0], RV.p01,                                   \
                 pk_fma_s1hi(ry[0], RV.p01, pk_fma_s1lo_s2hi(rz[0], RV.p23))); \
        v2f t1 = pk_fma_s1lo(rx[1], RV.p01,                                   \
                 pk_fma_s1hi(ry[1], RV.p01, pk_fma_s1lo_s2hi(rz[1], RV.p23))); \
        v2f t2 = pk_fma_s1lo(rx[2], RV.p01,                                   \
                 pk_fma_s1hi(ry[2], RV.p01, pk_fma_s1lo_s2hi(rz[2], RV.p23))); \
        v2f e0 = {EXP2(t0.x), EXP2(t0.y)};                                    \
        v2f e1 = {EXP2(t1.x), EXP2(t1.y)};                                    \
        v2f e2 = {EXP2(t2.x), EXP2(t2.y)};                                    \
        l0 = pk_add(l0, e0);                                                  \
        l1 = pk_add(l1, e1);                                                  \
        l2 = pk_add(l2, e2);                                                  \
        a0 = pk_fma(g0, e0, a0);                                              \
        a1 = pk_fma(g1, e1, a1);                                              \
        a2 = pk_fma(g2, e2, a2);                                              \
    }

    wq r0 = LDW(0), r1 = LDW(1), r2 = LDW(2), r3 = LDW(3);
    for (int jb = 0; jb < 60; jb += 4) {
        STEP(r0, jb + 0);
        r0 = LDW(jb + 4);
        STEP(r1, jb + 1);
        r1 = LDW(jb + 5);
        STEP(r2, jb + 2);
        r2 = LDW(jb + 6);
        STEP(r3, jb + 3);
        r3 = LDW(jb + 7);
    }
    STEP(r0, 60);
    STEP(r1, 61);
    STEP(r2, 62);
    STEP(r3, 63);
#undef STEP
#undef LDW

    s_red[w][d] = l0.x + l0.y + l1.x + l1.y + l2.x + l2.y;
    s_red[4 + w][d] = a0.x + a0.y + a1.x + a1.y + a2.x + a2.y;
    __syncthreads();
    if (tid < 64) {
        float L = s_red[0][d] + s_red[1][d] + s_red[2][d] + s_red[3][d];
        float A = s_red[4][d] + s_red[5][d] + s_red[6][d] + s_red[7][d];
        s_pre[d] = A / L;
    }
    __syncthreads();
    // out[pt][d] = sum_dd s_pre[dd] * sw[dd][d] + sb[d]
    float part = 0.f;
#pragma unroll
    for (int dd = 0; dd < 16; dd++) {
        int drow = w * 16 + dd;
        part = __builtin_fmaf(s_pre[drow], sw[drow * 64 + d], part);
    }
    s_red[w][d] = part;
    __syncthreads();
    if (tid < 64) {
        float o = s_red[0][d] + s_red[1][d] + s_red[2][d] + s_red[3][d] + sb[d];
        out[(size_t)pt * 64 + d] = o;
    }
    if (pt == 0 && tid == 0) out[(size_t)NPTS * 64] = 1024.0f;  // second output: N
}

extern "C" void kernel_launch(void* const* d_in, const int* in_sizes, int n_in,
                              void* d_out, int out_size, void* d_ws, size_t ws_size,
                              hipStream_t stream) {
    const float* feature = (const float*)d_in[0];
    const float* xyz = (const float*)d_in[1];
    const float* pw1 = (const float*)d_in[2];
    const float* pb1 = (const float*)d_in[3];
    const float* pw2 = (const float*)d_in[4];
    const float* pb2 = (const float*)d_in[5];
    const float* rw = (const float*)d_in[6];
    const float* rb = (const float*)d_in[7];
    const float* sw = (const float*)d_in[8];
    const float* sb = (const float*)d_in[9];
    float* out = (float*)d_out;

    char* ws = (char*)d_ws;
    float* feat = (float*)(ws);             // 512 KiB
    int* idx = (int*)(ws + 524288);         // 192 KiB
    float4* rwP = (float4*)(ws + 720896);   // 64 KiB

    prep_mlp_knn_kernel<<<1040, 256, 0, stream>>>(feature, xyz, pw1, pb1, pw2, pb2,
                                                  rw, rb, feat, idx, rwP);
    agg_kernel<<<NPTS, 256, 0, stream>>>(xyz, feat, idx, rwP, sw, sb, out);
}